// Round 1
// baseline (1184.132 us; speedup 1.0000x reference)
//
#include <hip/hip_runtime.h>
#include <math.h>

#define NND 50000
#define EPSB 1e-5f
#define SLOPE 0.2f

__device__ __forceinline__ float lrelu(float v) { return v > 0.f ? v : SLOPE * v; }

// ---------------- graph build (CSR by dst, self-loops via cnt init = 1) ----------------

__global__ void init_cnt_kernel(int* __restrict__ cnt, int n) {
    int i = blockIdx.x * 256 + threadIdx.x;
    if (i < n) cnt[i] = 1;  // self loop
}

__global__ void count_kernel(const int* __restrict__ ei, int E, int* __restrict__ cnt) {
    int e = blockIdx.x * 256 + threadIdx.x;
    if (e < E) atomicAdd(&cnt[ei[E + e]], 1);  // dst row = ei[1][e]
}

__global__ void scan1_kernel(const int* __restrict__ in, int n, int* __restrict__ outex,
                             int* __restrict__ bsum) {
    __shared__ int tmp[256];
    int tid = threadIdx.x;
    int i = blockIdx.x * 256 + tid;
    int v = (i < n) ? in[i] : 0;
    tmp[tid] = v;
    __syncthreads();
    for (int off = 1; off < 256; off <<= 1) {
        int t = (tid >= off) ? tmp[tid - off] : 0;
        __syncthreads();
        tmp[tid] += t;
        __syncthreads();
    }
    if (i < n) outex[i] = tmp[tid] - v;
    if (tid == 255) bsum[blockIdx.x] = tmp[255];
}

__global__ void scan2_kernel(const int* __restrict__ in, int n, int* __restrict__ outex) {
    __shared__ int tmp[256];
    int tid = threadIdx.x;
    int v = (tid < n) ? in[tid] : 0;
    tmp[tid] = v;
    __syncthreads();
    for (int off = 1; off < 256; off <<= 1) {
        int t = (tid >= off) ? tmp[tid - off] : 0;
        __syncthreads();
        tmp[tid] += t;
        __syncthreads();
    }
    if (tid < n) outex[tid] = tmp[tid] - v;
}

__global__ void scan3_kernel(int* __restrict__ rp, const int* __restrict__ boff,
                             int* __restrict__ fill, int n, int etot) {
    int i = blockIdx.x * 256 + threadIdx.x;
    if (i < n) {
        int v = rp[i] + boff[blockIdx.x];
        rp[i] = v;
        fill[i] = v;
    }
    if (i == 0) rp[n] = etot;
}

__global__ void scatter_self_kernel(int* __restrict__ fill, int* __restrict__ srcs, int n) {
    int i = blockIdx.x * 256 + threadIdx.x;
    if (i < n) {
        int p = atomicAdd(&fill[i], 1);
        srcs[p] = i;
    }
}

__global__ void scatter_edge_kernel(const int* __restrict__ ei, int E, int* __restrict__ fill,
                                    int* __restrict__ srcs) {
    int e = blockIdx.x * 256 + threadIdx.x;
    if (e < E) {
        int d = ei[E + e];
        int p = atomicAdd(&fill[d], 1);
        srcs[p] = ei[e];
    }
}

// ---------------- dense: h = X @ W^T  (W: [FOUT][K] row-major) ----------------
// 64-node x FOUT tile per block, 256 threads, 4x4 (or 4x8) register blocking.

template <int K, int FOUT>
__global__ __launch_bounds__(256) void gemm_kernel(const float* __restrict__ X,
                                                   const float* __restrict__ W,
                                                   float* __restrict__ H, int n) {
    constexpr int SW = FOUT + 4;  // padded LDS row stride (floats), %4==0 for float4
    constexpr int SX = 68;
    constexpr int NF = FOUT / 64;  // 1 or 2
    __shared__ float Wt[64 * SW];  // Wt[k][f]
    __shared__ float Xt[64 * SX];  // Xt[k][node]
    const int tid = threadIdx.x;
    const int nodeBase = blockIdx.x * 64;
    const int tx = tid & 15, ty = tid >> 4;

    float acc[4][4 * NF];
#pragma unroll
    for (int i = 0; i < 4; i++)
#pragma unroll
        for (int j = 0; j < 4 * NF; j++) acc[i][j] = 0.f;

    for (int kc = 0; kc < K; kc += 64) {
        // stage W chunk: coalesced read, transposed LDS write
        for (int idx = tid; idx < FOUT * 64; idx += 256) {
            int f = idx >> 6, kk = idx & 63;
            Wt[kk * SW + f] = W[f * K + kc + kk];
        }
        // stage X^T chunk: float4 global reads
        for (int idx = tid; idx < 64 * 16; idx += 256) {
            int r = idx >> 4, c4 = idx & 15;
            int node = nodeBase + r;
            float4 v = make_float4(0.f, 0.f, 0.f, 0.f);
            if (node < n) v = ((const float4*)X)[node * (K / 4) + (kc >> 2) + c4];
            Xt[(c4 * 4 + 0) * SX + r] = v.x;
            Xt[(c4 * 4 + 1) * SX + r] = v.y;
            Xt[(c4 * 4 + 2) * SX + r] = v.z;
            Xt[(c4 * 4 + 3) * SX + r] = v.w;
        }
        __syncthreads();
#pragma unroll 16
        for (int k = 0; k < 64; k++) {
            const float4 xv = *(const float4*)(Xt + k * SX + ty * 4);
            const float4 wv = *(const float4*)(Wt + k * SW + tx * 4);
            const float xa[4] = {xv.x, xv.y, xv.z, xv.w};
            float wa[4 * NF];
            wa[0] = wv.x; wa[1] = wv.y; wa[2] = wv.z; wa[3] = wv.w;
            if constexpr (NF == 2) {
                const float4 wv2 = *(const float4*)(Wt + k * SW + 64 + tx * 4);
                wa[4] = wv2.x; wa[5] = wv2.y; wa[6] = wv2.z; wa[7] = wv2.w;
            }
#pragma unroll
            for (int i = 0; i < 4; i++)
#pragma unroll
                for (int j = 0; j < 4 * NF; j++) acc[i][j] += xa[i] * wa[j];
        }
        __syncthreads();
    }
#pragma unroll
    for (int i = 0; i < 4; i++) {
        int node = nodeBase + ty * 4 + i;
        if (node < n) {
            float4 o;
            o.x = acc[i][0]; o.y = acc[i][1]; o.z = acc[i][2]; o.w = acc[i][3];
            ((float4*)H)[node * (FOUT / 4) + tx] = o;
            if constexpr (NF == 2) {
                float4 o2;
                o2.x = acc[i][4]; o2.y = acc[i][5]; o2.z = acc[i][6]; o2.w = acc[i][7];
                ((float4*)H)[node * (FOUT / 4) + 16 + tx] = o2;
            }
        }
    }
}

// ---------------- alpha_s / alpha_d = h . a_src / h . a_dst (wave per node) ----------------

template <int F>
__global__ __launch_bounds__(256) void alpha_kernel(const float* __restrict__ h,
                                                    const float* __restrict__ asrc,
                                                    const float* __restrict__ adst,
                                                    float* __restrict__ as_o,
                                                    float* __restrict__ ad_o, int n) {
    const int lane = threadIdx.x & 63;
    const int node = blockIdx.x * 4 + (threadIdx.x >> 6);
    if (node >= n) return;
    float v0 = h[node * F + lane];
    float s = v0 * asrc[lane];
    float d = v0 * adst[lane];
    if constexpr (F == 128) {
        float v1 = h[node * F + 64 + lane];
        s += v1 * asrc[64 + lane];
        d += v1 * adst[64 + lane];
    }
#pragma unroll
    for (int off = 32; off; off >>= 1) {
        s += __shfl_xor(s, off, 64);
        d += __shfl_xor(d, off, 64);
    }
    if (lane == 0) {
        as_o[node] = s;
        ad_o[node] = d;
    }
}

// ---------------- sparse: segment softmax + aggregation, wave per dst row ----------------

template <int F, bool FINAL>
__global__ __launch_bounds__(256) void edge_kernel(
    const int* __restrict__ rp, const int* __restrict__ srcs, const float* __restrict__ as_,
    const float* __restrict__ ad_, const float* __restrict__ h, const float* __restrict__ bias,
    float* __restrict__ y, float* __restrict__ bnsum, float* __restrict__ bnsq,
    const float* __restrict__ xin, float* __restrict__ odiff, float* __restrict__ oxhat) {
    const int lane = threadIdx.x & 63;
    const int wid = blockIdx.x * 4 + (threadIdx.x >> 6);
    const int nw = gridDim.x * 4;
    const float b0 = bias[lane];
    const float b1 = (F == 128) ? bias[64 + lane] : 0.f;
    float s0 = 0.f, q0 = 0.f, s1 = 0.f, q1 = 0.f;

    for (int row = wid; row < NND; row += nw) {
        const int beg = rp[row], end = rp[row + 1];
        const float ad = ad_[row];
        // pass 1: max
        float m = -INFINITY;
        for (int i = beg + lane; i < end; i += 64) m = fmaxf(m, lrelu(as_[srcs[i]] + ad));
#pragma unroll
        for (int off = 32; off; off >>= 1) m = fmaxf(m, __shfl_xor(m, off, 64));
        // pass 2: sum of exp
        float ss = 0.f;
        for (int i = beg + lane; i < end; i += 64) ss += expf(lrelu(as_[srcs[i]] + ad) - m);
#pragma unroll
        for (int off = 32; off; off >>= 1) ss += __shfl_xor(ss, off, 64);
        const float inv = 1.f / (ss + 1e-16f);
        // pass 3: weighted aggregation, lanes over features
        float a0 = 0.f, a1 = 0.f;
        for (int i = beg; i < end; i++) {
            int s = srcs[i];
            float w = expf(lrelu(as_[s] + ad) - m) * inv;
            a0 += w * h[s * F + lane];
            if constexpr (F == 128) a1 += w * h[s * F + 64 + lane];
        }
        float y0 = fmaxf(a0 + b0, 0.f);
        float y1 = 0.f;
        if constexpr (F == 128) y1 = fmaxf(a1 + b1, 0.f);
        if constexpr (FINAL) {
            float xv0 = xin[row * F + lane];
            oxhat[row * F + lane] = y0;
            odiff[row * F + lane] = fabsf(xv0 - y0);
            if constexpr (F == 128) {
                float xv1 = xin[row * F + 64 + lane];
                oxhat[row * F + 64 + lane] = y1;
                odiff[row * F + 64 + lane] = fabsf(xv1 - y1);
            }
        } else {
            y[row * F + lane] = y0;
            s0 += y0;
            q0 += y0 * y0;
            if constexpr (F == 128) {
                y[row * F + 64 + lane] = y1;
                s1 += y1;
                q1 += y1 * y1;
            }
        }
    }
    if constexpr (!FINAL) {
        atomicAdd(&bnsum[lane], s0);
        atomicAdd(&bnsq[lane], q0);
        if constexpr (F == 128) {
            atomicAdd(&bnsum[64 + lane], s1);
            atomicAdd(&bnsq[64 + lane], q1);
        }
    }
}

// ---------------- batch norm apply ----------------

template <int F>
__global__ void bn_kernel(const float* __restrict__ y, const float* __restrict__ sum,
                          const float* __restrict__ sq, const float* __restrict__ g,
                          const float* __restrict__ be, float* __restrict__ z, int total) {
    int idx = blockIdx.x * blockDim.x + threadIdx.x;
    int stride = gridDim.x * blockDim.x;
    const float invn = 1.f / (float)NND;
    for (; idx < total; idx += stride) {
        int f = idx & (F - 1);
        float mu = sum[f] * invn;
        float var = sq[f] * invn - mu * mu;
        float r = rsqrtf(var + EPSB);
        z[idx] = g[f] * (y[idx] - mu) * r + be[f];
    }
}

// ---------------- host launch ----------------

extern "C" void kernel_launch(void* const* d_in, const int* in_sizes, int n_in, void* d_out,
                              int out_size, void* d_ws, size_t ws_size, hipStream_t stream) {
    const float* x = (const float*)d_in[0];
    const int* ei = (const int*)d_in[1];
    const int E = in_sizes[1] / 2;
    const float* W1 = (const float*)d_in[2];
    const float* a1s = (const float*)d_in[3];
    const float* a1d = (const float*)d_in[4];
    const float* b1 = (const float*)d_in[5];
    const float* g1 = (const float*)d_in[6];
    const float* be1 = (const float*)d_in[7];
    const float* W2 = (const float*)d_in[8];
    const float* a2s = (const float*)d_in[9];
    const float* a2d = (const float*)d_in[10];
    const float* b2 = (const float*)d_in[11];
    const float* g2 = (const float*)d_in[12];
    const float* be2 = (const float*)d_in[13];
    const float* W3 = (const float*)d_in[14];
    const float* a3s = (const float*)d_in[15];
    const float* a3d = (const float*)d_in[16];
    const float* b3 = (const float*)d_in[17];
    const float* g3 = (const float*)d_in[18];
    const float* be3 = (const float*)d_in[19];
    const float* W4 = (const float*)d_in[20];
    const float* a4s = (const float*)d_in[21];
    const float* a4d = (const float*)d_in[22];
    const float* b4 = (const float*)d_in[23];

    const int Etot = E + NND;

    // workspace carve (256B aligned)
    char* w = (char*)d_ws;
    auto alloc = [&](size_t bytes) {
        void* p = (void*)w;
        w += (bytes + 255) & ~(size_t)255;
        return p;
    };
    int* cnt = (int*)alloc((size_t)NND * 4);
    int* rp = (int*)alloc((size_t)(NND + 1) * 4);
    int* fill = (int*)alloc((size_t)NND * 4);
    int* bsum = (int*)alloc(256 * 4);
    int* bsum2 = (int*)alloc(256 * 4);
    int* srcs = (int*)alloc((size_t)Etot * 4);
    float* bufA = (float*)alloc((size_t)NND * 128 * 4);
    float* bufB = (float*)alloc((size_t)NND * 128 * 4);
    float* asb = (float*)alloc((size_t)NND * 4);
    float* adb = (float*)alloc((size_t)NND * 4);
    float* stats = (float*)alloc(768 * 4);

    const int nblk = (NND + 255) / 256;       // 196
    const int egrid = (E + 255) / 256;        // 3125
    const int ggrid = (NND + 63) / 64;        // 782
    const int agrid = (NND + 3) / 4;          // 12500
    const int xgrid = 1024;                   // edge kernel blocks
    const int bgrid = 2048;                   // bn kernel blocks

    hipMemsetAsync(stats, 0, 768 * 4, stream);

    // graph build
    init_cnt_kernel<<<nblk, 256, 0, stream>>>(cnt, NND);
    count_kernel<<<egrid, 256, 0, stream>>>(ei, E, cnt);
    scan1_kernel<<<nblk, 256, 0, stream>>>(cnt, NND, rp, bsum);
    scan2_kernel<<<1, 256, 0, stream>>>(bsum, nblk, bsum2);
    scan3_kernel<<<nblk, 256, 0, stream>>>(rp, bsum2, fill, NND, Etot);
    scatter_self_kernel<<<nblk, 256, 0, stream>>>(fill, srcs, NND);
    scatter_edge_kernel<<<egrid, 256, 0, stream>>>(ei, E, fill, srcs);

    // ---- layer 1: x[N,128] -> h bufA[N,64]; y bufB; z bufA
    gemm_kernel<128, 64><<<ggrid, 256, 0, stream>>>(x, W1, bufA, NND);
    alpha_kernel<64><<<agrid, 256, 0, stream>>>(bufA, a1s, a1d, asb, adb, NND);
    edge_kernel<64, false><<<xgrid, 256, 0, stream>>>(rp, srcs, asb, adb, bufA, b1, bufB,
                                                      stats + 0, stats + 128, nullptr, nullptr,
                                                      nullptr);
    bn_kernel<64><<<bgrid, 256, 0, stream>>>(bufB, stats + 0, stats + 128, g1, be1, bufA,
                                             NND * 64);

    // ---- layer 2: bufA -> h bufB; y bufA; z bufB
    gemm_kernel<64, 64><<<ggrid, 256, 0, stream>>>(bufA, W2, bufB, NND);
    alpha_kernel<64><<<agrid, 256, 0, stream>>>(bufB, a2s, a2d, asb, adb, NND);
    edge_kernel<64, false><<<xgrid, 256, 0, stream>>>(rp, srcs, asb, adb, bufB, b2, bufA,
                                                      stats + 256, stats + 384, nullptr, nullptr,
                                                      nullptr);
    bn_kernel<64><<<bgrid, 256, 0, stream>>>(bufA, stats + 256, stats + 384, g2, be2, bufB,
                                             NND * 64);

    // ---- layer 3: bufB -> h bufA; y bufB; z bufA
    gemm_kernel<64, 64><<<ggrid, 256, 0, stream>>>(bufB, W3, bufA, NND);
    alpha_kernel<64><<<agrid, 256, 0, stream>>>(bufA, a3s, a3d, asb, adb, NND);
    edge_kernel<64, false><<<xgrid, 256, 0, stream>>>(rp, srcs, asb, adb, bufA, b3, bufB,
                                                      stats + 512, stats + 640, nullptr, nullptr,
                                                      nullptr);
    bn_kernel<64><<<bgrid, 256, 0, stream>>>(bufB, stats + 512, stats + 640, g3, be3, bufA,
                                             NND * 64);

    // ---- layer 4 (final): bufA -> h bufB[N,128]; write diff/xhat to d_out
    float* odiff = (float*)d_out;
    float* oxhat = (float*)d_out + (size_t)NND * 128;
    gemm_kernel<64, 128><<<ggrid, 256, 0, stream>>>(bufA, W4, bufB, NND);
    alpha_kernel<128><<<agrid, 256, 0, stream>>>(bufB, a4s, a4d, asb, adb, NND);
    edge_kernel<128, true><<<xgrid, 256, 0, stream>>>(rp, srcs, asb, adb, bufB, b4, nullptr,
                                                      nullptr, nullptr, x, odiff, oxhat);
}

// Round 2
// 600.194 us; speedup vs baseline: 1.9729x; 1.9729x over previous
//
#include <hip/hip_runtime.h>
#include <math.h>

#define NND 50000
#define EPSB 1e-5f
#define SLOPE 0.2f
#define DEGCAP 128

__device__ __forceinline__ float lrelu(float v) { return v > 0.f ? v : SLOPE * v; }

// ---------------- graph build (CSR by dst, self-loops via cnt init = 1) ----------------

__global__ void init_cnt_kernel(int* __restrict__ cnt, int n) {
    int i = blockIdx.x * 256 + threadIdx.x;
    if (i < n) cnt[i] = 1;  // self loop
}

__global__ void count_kernel(const int* __restrict__ ei, int E, int* __restrict__ cnt) {
    int e = blockIdx.x * 256 + threadIdx.x;
    if (e < E) atomicAdd(&cnt[ei[E + e]], 1);  // dst row = ei[1][e]
}

__global__ void scan1_kernel(const int* __restrict__ in, int n, int* __restrict__ outex,
                             int* __restrict__ bsum) {
    __shared__ int tmp[256];
    int tid = threadIdx.x;
    int i = blockIdx.x * 256 + tid;
    int v = (i < n) ? in[i] : 0;
    tmp[tid] = v;
    __syncthreads();
    for (int off = 1; off < 256; off <<= 1) {
        int t = (tid >= off) ? tmp[tid - off] : 0;
        __syncthreads();
        tmp[tid] += t;
        __syncthreads();
    }
    if (i < n) outex[i] = tmp[tid] - v;
    if (tid == 255) bsum[blockIdx.x] = tmp[255];
}

__global__ void scan2_kernel(const int* __restrict__ in, int n, int* __restrict__ outex) {
    __shared__ int tmp[256];
    int tid = threadIdx.x;
    int v = (tid < n) ? in[tid] : 0;
    tmp[tid] = v;
    __syncthreads();
    for (int off = 1; off < 256; off <<= 1) {
        int t = (tid >= off) ? tmp[tid - off] : 0;
        __syncthreads();
        tmp[tid] += t;
        __syncthreads();
    }
    if (tid < n) outex[tid] = tmp[tid] - v;
}

__global__ void scan3_kernel(int* __restrict__ rp, const int* __restrict__ boff,
                             int* __restrict__ fill, int n, int etot) {
    int i = blockIdx.x * 256 + threadIdx.x;
    if (i < n) {
        int v = rp[i] + boff[blockIdx.x];
        rp[i] = v;
        fill[i] = v;
    }
    if (i == 0) rp[n] = etot;
}

__global__ void scatter_self_kernel(int* __restrict__ fill, int* __restrict__ srcs, int n) {
    int i = blockIdx.x * 256 + threadIdx.x;
    if (i < n) {
        int p = atomicAdd(&fill[i], 1);
        srcs[p] = i;
    }
}

__global__ void scatter_edge_kernel(const int* __restrict__ ei, int E, int* __restrict__ fill,
                                    int* __restrict__ srcs) {
    int e = blockIdx.x * 256 + threadIdx.x;
    if (e < E) {
        int d = ei[E + e];
        int p = atomicAdd(&fill[d], 1);
        srcs[p] = ei[e];
    }
}

// ---------------- dense: h = X' @ W^T with fused input-BN and fused alpha epilogue --------
// X' = bnscale[f]*X + bnshift[f] when bnsum!=nullptr (BN of PREVIOUS layer applied lazily).
// Epilogue also computes as_o = h . asrc, ad_o = h . adst via 16-lane shuffle reduce.

template <int K, int FOUT>
__global__ __launch_bounds__(256) void gemm_kernel(
    const float* __restrict__ X, const float* __restrict__ W, float* __restrict__ H, int n,
    const float* __restrict__ bnsum, const float* __restrict__ bnsq, const float* __restrict__ g,
    const float* __restrict__ be, const float* __restrict__ asrc, const float* __restrict__ adst,
    float* __restrict__ as_o, float* __restrict__ ad_o) {
    constexpr int SW = FOUT + 4;  // padded LDS row stride (floats), %4==0 for float4
    constexpr int SX = 68;
    constexpr int NF = FOUT / 64;  // 1 or 2
    __shared__ float Wt[64 * SW];  // Wt[k][f]
    __shared__ float Xt[64 * SX];  // Xt[k][node]
    __shared__ float bnsc[K];
    __shared__ float bnsh[K];
    const int tid = threadIdx.x;
    const int nodeBase = blockIdx.x * 64;
    const int tx = tid & 15, ty = tid >> 4;
    const bool doBN = (bnsum != nullptr);

    if (doBN) {
        const float invn = 1.f / (float)NND;
        for (int f = tid; f < K; f += 256) {
            float mu = bnsum[f] * invn;
            float var = bnsq[f] * invn - mu * mu;
            float r = rsqrtf(var + EPSB);
            float sc = g[f] * r;
            bnsc[f] = sc;
            bnsh[f] = be[f] - mu * sc;
        }
    }
    __syncthreads();

    float acc[4][4 * NF];
#pragma unroll
    for (int i = 0; i < 4; i++)
#pragma unroll
        for (int j = 0; j < 4 * NF; j++) acc[i][j] = 0.f;

    for (int kc = 0; kc < K; kc += 64) {
        // stage W chunk: coalesced read, transposed LDS write
        for (int idx = tid; idx < FOUT * 64; idx += 256) {
            int f = idx >> 6, kk = idx & 63;
            Wt[kk * SW + f] = W[f * K + kc + kk];
        }
        // stage X^T chunk: float4 global reads, fused BN
        for (int idx = tid; idx < 64 * 16; idx += 256) {
            int r = idx >> 4, c4 = idx & 15;
            int node = nodeBase + r;
            float4 v = make_float4(0.f, 0.f, 0.f, 0.f);
            if (node < n) {
                v = ((const float4*)X)[node * (K / 4) + (kc >> 2) + c4];
                if (doBN) {
                    int f = kc + c4 * 4;
                    v.x = v.x * bnsc[f + 0] + bnsh[f + 0];
                    v.y = v.y * bnsc[f + 1] + bnsh[f + 1];
                    v.z = v.z * bnsc[f + 2] + bnsh[f + 2];
                    v.w = v.w * bnsc[f + 3] + bnsh[f + 3];
                }
            }
            Xt[(c4 * 4 + 0) * SX + r] = v.x;
            Xt[(c4 * 4 + 1) * SX + r] = v.y;
            Xt[(c4 * 4 + 2) * SX + r] = v.z;
            Xt[(c4 * 4 + 3) * SX + r] = v.w;
        }
        __syncthreads();
#pragma unroll 16
        for (int k = 0; k < 64; k++) {
            const float4 xv = *(const float4*)(Xt + k * SX + ty * 4);
            const float4 wv = *(const float4*)(Wt + k * SW + tx * 4);
            const float xa[4] = {xv.x, xv.y, xv.z, xv.w};
            float wa[4 * NF];
            wa[0] = wv.x; wa[1] = wv.y; wa[2] = wv.z; wa[3] = wv.w;
            if constexpr (NF == 2) {
                const float4 wv2 = *(const float4*)(Wt + k * SW + 64 + tx * 4);
                wa[4] = wv2.x; wa[5] = wv2.y; wa[6] = wv2.z; wa[7] = wv2.w;
            }
#pragma unroll
            for (int i = 0; i < 4; i++)
#pragma unroll
                for (int j = 0; j < 4 * NF; j++) acc[i][j] += xa[i] * wa[j];
        }
        __syncthreads();
    }
#pragma unroll
    for (int i = 0; i < 4; i++) {
        int node = nodeBase + ty * 4 + i;
        if (node < n) {
            float4 o;
            o.x = acc[i][0]; o.y = acc[i][1]; o.z = acc[i][2]; o.w = acc[i][3];
            ((float4*)H)[node * (FOUT / 4) + tx] = o;
            if constexpr (NF == 2) {
                float4 o2;
                o2.x = acc[i][4]; o2.y = acc[i][5]; o2.z = acc[i][6]; o2.w = acc[i][7];
                ((float4*)H)[node * (FOUT / 4) + 16 + tx] = o2;
            }
        }
    }
    // fused alpha epilogue: as/ad = h . asrc / h . adst, reduce over the 16 tx lanes
    if (as_o) {
        float asv[4 * NF], adv[4 * NF];
#pragma unroll
        for (int j = 0; j < 4; j++) {
            asv[j] = asrc[tx * 4 + j];
            adv[j] = adst[tx * 4 + j];
            if constexpr (NF == 2) {
                asv[4 + j] = asrc[64 + tx * 4 + j];
                adv[4 + j] = adst[64 + tx * 4 + j];
            }
        }
#pragma unroll
        for (int i = 0; i < 4; i++) {
            int node = nodeBase + ty * 4 + i;
            float ps = 0.f, pd = 0.f;
#pragma unroll
            for (int j = 0; j < 4 * NF; j++) {
                ps += acc[i][j] * asv[j];
                pd += acc[i][j] * adv[j];
            }
#pragma unroll
            for (int off = 1; off < 16; off <<= 1) {
                ps += __shfl_xor(ps, off, 64);
                pd += __shfl_xor(pd, off, 64);
            }
            if (tx == 0 && node < n) {
                as_o[node] = ps;
                ad_o[node] = pd;
            }
        }
    }
}

// ---------------- sparse: segment softmax + aggregation, wave per dst row ----------------
// Phase 1 (lanes over edges): gather src + logit into per-wave LDS, wave-reduce max & sum.
// Phase 2 (lanes over features): aggregation unrolled x4 for 4 in-flight gathers.

template <int F, bool FINAL>
__global__ __launch_bounds__(256) void edge_kernel(
    const int* __restrict__ rp, const int* __restrict__ srcs, const float* __restrict__ as_,
    const float* __restrict__ ad_, const float* __restrict__ h, const float* __restrict__ bias,
    float* __restrict__ y, float* __restrict__ bnsum, float* __restrict__ bnsq,
    const float* __restrict__ xin, float* __restrict__ odiff, float* __restrict__ oxhat) {
    __shared__ float wsh[4][DEGCAP];
    __shared__ int ssh[4][DEGCAP];
    __shared__ float redS[4][64];
    __shared__ float redQ[4][64];
    const int lane = threadIdx.x & 63;
    const int wslot = threadIdx.x >> 6;
    const int wid = blockIdx.x * 4 + wslot;
    const int nw = gridDim.x * 4;
    const float b0 = bias[lane];
    const float b1 = (F == 128) ? bias[64 + lane] : 0.f;
    float s0 = 0.f, q0 = 0.f;

    for (int row = wid; row < NND; row += nw) {
        const int beg = rp[row], end = rp[row + 1];
        const int deg = end - beg;
        const float ad = ad_[row];
        float a0 = 0.f, a1 = 0.f;
        float inv;
        if (deg <= DEGCAP) {
            // phase 1: lanes over edges
            float m = -INFINITY;
            for (int i = lane; i < deg; i += 64) {
                int s = srcs[beg + i];
                float e = lrelu(as_[s] + ad);
                ssh[wslot][i] = s;
                wsh[wslot][i] = e;
                m = fmaxf(m, e);
            }
#pragma unroll
            for (int off = 32; off; off >>= 1) m = fmaxf(m, __shfl_xor(m, off, 64));
            float ss = 0.f;
            for (int i = lane; i < deg; i += 64) {
                float wv = __expf(wsh[wslot][i] - m);
                wsh[wslot][i] = wv;
                ss += wv;
            }
#pragma unroll
            for (int off = 32; off; off >>= 1) ss += __shfl_xor(ss, off, 64);
            inv = 1.f / (ss + 1e-16f);
            // phase 2: lanes over features, x4 unroll (4 gathers in flight)
            int i = 0;
            for (; i + 4 <= deg; i += 4) {
                int sa = ssh[wslot][i + 0], sb = ssh[wslot][i + 1];
                int sc = ssh[wslot][i + 2], sd = ssh[wslot][i + 3];
                float wa = wsh[wslot][i + 0], wb = wsh[wslot][i + 1];
                float wc = wsh[wslot][i + 2], wd = wsh[wslot][i + 3];
                float ha = h[(size_t)sa * F + lane];
                float hb = h[(size_t)sb * F + lane];
                float hc = h[(size_t)sc * F + lane];
                float hd = h[(size_t)sd * F + lane];
                a0 += wa * ha;
                a0 += wb * hb;
                a0 += wc * hc;
                a0 += wd * hd;
                if constexpr (F == 128) {
                    float ha2 = h[(size_t)sa * F + 64 + lane];
                    float hb2 = h[(size_t)sb * F + 64 + lane];
                    float hc2 = h[(size_t)sc * F + 64 + lane];
                    float hd2 = h[(size_t)sd * F + 64 + lane];
                    a1 += wa * ha2;
                    a1 += wb * hb2;
                    a1 += wc * hc2;
                    a1 += wd * hd2;
                }
            }
            for (; i < deg; i++) {
                int s = ssh[wslot][i];
                float wv = wsh[wslot][i];
                a0 += wv * h[(size_t)s * F + lane];
                if constexpr (F == 128) a1 += wv * h[(size_t)s * F + 64 + lane];
            }
        } else {
            // fallback (deg > DEGCAP): 3-pass recompute, never expected on this graph
            float m = -INFINITY;
            for (int i = beg + lane; i < end; i += 64) m = fmaxf(m, lrelu(as_[srcs[i]] + ad));
#pragma unroll
            for (int off = 32; off; off >>= 1) m = fmaxf(m, __shfl_xor(m, off, 64));
            float ss = 0.f;
            for (int i = beg + lane; i < end; i += 64) ss += __expf(lrelu(as_[srcs[i]] + ad) - m);
#pragma unroll
            for (int off = 32; off; off >>= 1) ss += __shfl_xor(ss, off, 64);
            inv = 1.f / (ss + 1e-16f);
            for (int i = beg; i < end; i++) {
                int s = srcs[i];
                float wv = __expf(lrelu(as_[s] + ad) - m);
                a0 += wv * h[(size_t)s * F + lane];
                if constexpr (F == 128) a1 += wv * h[(size_t)s * F + 64 + lane];
            }
        }
        float y0 = fmaxf(a0 * inv + b0, 0.f);
        float y1 = 0.f;
        if constexpr (F == 128) y1 = fmaxf(a1 * inv + b1, 0.f);
        if constexpr (FINAL) {
            float xv0 = xin[(size_t)row * F + lane];
            oxhat[(size_t)row * F + lane] = y0;
            odiff[(size_t)row * F + lane] = fabsf(xv0 - y0);
            if constexpr (F == 128) {
                float xv1 = xin[(size_t)row * F + 64 + lane];
                oxhat[(size_t)row * F + 64 + lane] = y1;
                odiff[(size_t)row * F + 64 + lane] = fabsf(xv1 - y1);
            }
        } else {
            y[(size_t)row * F + lane] = y0;
            s0 += y0;
            q0 += y0 * y0;
        }
    }
    if constexpr (!FINAL) {
        // block-level reduce (4 waves) then one atomic per block per feature
        redS[wslot][lane] = s0;
        redQ[wslot][lane] = q0;
        __syncthreads();
        if (wslot == 0) {
            float ts = redS[0][lane] + redS[1][lane] + redS[2][lane] + redS[3][lane];
            float tq = redQ[0][lane] + redQ[1][lane] + redQ[2][lane] + redQ[3][lane];
            atomicAdd(&bnsum[lane], ts);
            atomicAdd(&bnsq[lane], tq);
        }
    }
}

// ---------------- host launch ----------------

extern "C" void kernel_launch(void* const* d_in, const int* in_sizes, int n_in, void* d_out,
                              int out_size, void* d_ws, size_t ws_size, hipStream_t stream) {
    const float* x = (const float*)d_in[0];
    const int* ei = (const int*)d_in[1];
    const int E = in_sizes[1] / 2;
    const float* W1 = (const float*)d_in[2];
    const float* a1s = (const float*)d_in[3];
    const float* a1d = (const float*)d_in[4];
    const float* b1 = (const float*)d_in[5];
    const float* g1 = (const float*)d_in[6];
    const float* be1 = (const float*)d_in[7];
    const float* W2 = (const float*)d_in[8];
    const float* a2s = (const float*)d_in[9];
    const float* a2d = (const float*)d_in[10];
    const float* b2 = (const float*)d_in[11];
    const float* g2 = (const float*)d_in[12];
    const float* be2 = (const float*)d_in[13];
    const float* W3 = (const float*)d_in[14];
    const float* a3s = (const float*)d_in[15];
    const float* a3d = (const float*)d_in[16];
    const float* b3 = (const float*)d_in[17];
    const float* g3 = (const float*)d_in[18];
    const float* be3 = (const float*)d_in[19];
    const float* W4 = (const float*)d_in[20];
    const float* a4s = (const float*)d_in[21];
    const float* a4d = (const float*)d_in[22];
    const float* b4 = (const float*)d_in[23];

    const int Etot = E + NND;

    // workspace carve (256B aligned)
    char* w = (char*)d_ws;
    auto alloc = [&](size_t bytes) {
        void* p = (void*)w;
        w += (bytes + 255) & ~(size_t)255;
        return p;
    };
    int* cnt = (int*)alloc((size_t)NND * 4);
    int* rp = (int*)alloc((size_t)(NND + 1) * 4);
    int* fill = (int*)alloc((size_t)NND * 4);
    int* bsum = (int*)alloc(256 * 4);
    int* bsum2 = (int*)alloc(256 * 4);
    int* srcs = (int*)alloc((size_t)Etot * 4);
    float* bufA = (float*)alloc((size_t)NND * 128 * 4);
    float* bufB = (float*)alloc((size_t)NND * 128 * 4);
    float* asb = (float*)alloc((size_t)NND * 4);
    float* adb = (float*)alloc((size_t)NND * 4);
    float* stats = (float*)alloc(384 * 4);  // 3 layers x (sum[64], sq[64])

    const int nblk = (NND + 255) / 256;  // 196
    const int egrid = (E + 255) / 256;   // 3125
    const int ggrid = (NND + 63) / 64;   // 782
    const int xgrid = 2048;              // edge kernel blocks (8192 waves)

    hipMemsetAsync(stats, 0, 384 * 4, stream);

    // graph build
    init_cnt_kernel<<<nblk, 256, 0, stream>>>(cnt, NND);
    count_kernel<<<egrid, 256, 0, stream>>>(ei, E, cnt);
    scan1_kernel<<<nblk, 256, 0, stream>>>(cnt, NND, rp, bsum);
    scan2_kernel<<<1, 256, 0, stream>>>(bsum, nblk, bsum2);
    scan3_kernel<<<nblk, 256, 0, stream>>>(rp, bsum2, fill, NND, Etot);
    scatter_self_kernel<<<nblk, 256, 0, stream>>>(fill, srcs, NND);
    scatter_edge_kernel<<<egrid, 256, 0, stream>>>(ei, E, fill, srcs);

    // ---- layer 1: x[N,128] -> h bufA[N,64]; edge -> y1 bufB (pre-BN), stats[0..127]
    gemm_kernel<128, 64><<<ggrid, 256, 0, stream>>>(x, W1, bufA, NND, nullptr, nullptr, nullptr,
                                                    nullptr, a1s, a1d, asb, adb);
    edge_kernel<64, false><<<xgrid, 256, 0, stream>>>(rp, srcs, asb, adb, bufA, b1, bufB,
                                                      stats + 0, stats + 64, nullptr, nullptr,
                                                      nullptr);

    // ---- layer 2: gemm applies BN1 to bufB inline -> h bufA; edge -> y2 bufB
    gemm_kernel<64, 64><<<ggrid, 256, 0, stream>>>(bufB, W2, bufA, NND, stats + 0, stats + 64,
                                                   g1, be1, a2s, a2d, asb, adb);
    edge_kernel<64, false><<<xgrid, 256, 0, stream>>>(rp, srcs, asb, adb, bufA, b2, bufB,
                                                      stats + 128, stats + 192, nullptr, nullptr,
                                                      nullptr);

    // ---- layer 3: gemm applies BN2 -> h bufA; edge -> y3 bufB
    gemm_kernel<64, 64><<<ggrid, 256, 0, stream>>>(bufB, W3, bufA, NND, stats + 128, stats + 192,
                                                   g2, be2, a3s, a3d, asb, adb);
    edge_kernel<64, false><<<xgrid, 256, 0, stream>>>(rp, srcs, asb, adb, bufA, b3, bufB,
                                                      stats + 256, stats + 320, nullptr, nullptr,
                                                      nullptr);

    // ---- layer 4 (final): gemm applies BN3 -> h bufA[N,128]; edge writes diff/xhat
    float* odiff = (float*)d_out;
    float* oxhat = (float*)d_out + (size_t)NND * 128;
    gemm_kernel<64, 128><<<ggrid, 256, 0, stream>>>(bufB, W4, bufA, NND, stats + 256, stats + 320,
                                                    g3, be3, a4s, a4d, asb, adb);
    edge_kernel<128, true><<<xgrid, 256, 0, stream>>>(rp, srcs, asb, adb, bufA, b4, nullptr,
                                                      nullptr, nullptr, x, odiff, oxhat);
}